// Round 7
// baseline (394.847 us; speedup 1.0000x reference)
//
#include <hip/hip_runtime.h>
#include <math.h>

#define B_   8
#define C_   768
#define T_   1024
#define BT_  (B_*T_)       // 8192
#define WSZ  (C_*C_)       // 589824 per weight matrix

using f16x8 = __attribute__((ext_vector_type(8))) _Float16;
using f32x4 = __attribute__((ext_vector_type(4))) float;
typedef unsigned short u16;

// ---- fp16 helpers ----
__device__ inline u16 f16b(float x) {
    _Float16 h = (_Float16)x;
    return __builtin_bit_cast(u16, h);
}
__device__ inline float f16f(u16 b) {
    return (float)__builtin_bit_cast(_Float16, b);
}

// ---------------------------------------------------------------------------
// Kernel 0: all 5 weight mats fp32 -> fp16 in one launch.
// ---------------------------------------------------------------------------
__global__ __launch_bounds__(256) void wconv_all(
    const float* __restrict__ W0, const float* __restrict__ W1,
    const float* __restrict__ W2, const float* __restrict__ W3,
    const float* __restrict__ W4, u16* __restrict__ wbuf) {
    int mat = blockIdx.y;
    const float* W = (mat == 0) ? W0 : (mat == 1) ? W1 : (mat == 2) ? W2
                   : (mat == 3) ? W3 : W4;
    u16* o = wbuf + (size_t)mat * WSZ;
    int i = (blockIdx.x * 256 + threadIdx.x) * 4;
    float4 w = *(const float4*)(W + i);
    ushort4 h;
    h.x = f16b(w.x);
    h.y = f16b(w.y);
    h.z = f16b(w.z);
    h.w = f16b(w.w);
    *(ushort4*)(o + i) = h;
}

// ---------------------------------------------------------------------------
// Kernel 1: LayerNorm with (B,C,T)->(B*T,C) transpose; writes fp16.
// ---------------------------------------------------------------------------
__global__ __launch_bounds__(256) void ln_kernel(const float* __restrict__ x,
                                                 const float* __restrict__ gamma,
                                                 const float* __restrict__ beta,
                                                 u16* __restrict__ xh) {
    int row = blockIdx.x;
    int b = row >> 10;
    int t = row & 1023;
    int tid = threadIdx.x;
    const float* xb = x + (size_t)b * C_ * T_ + t;
    float v0 = xb[(size_t)(tid      ) * T_];
    float v1 = xb[(size_t)(tid + 256) * T_];
    float v2 = xb[(size_t)(tid + 512) * T_];
    float s  = v0 + v1 + v2;
    float sq = v0 * v0 + v1 * v1 + v2 * v2;
    #pragma unroll
    for (int m = 1; m < 64; m <<= 1) {
        s  += __shfl_xor(s,  m);
        sq += __shfl_xor(sq, m);
    }
    __shared__ float ss[4], ssq[4];
    int wid = tid >> 6;
    if ((tid & 63) == 0) { ss[wid] = s; ssq[wid] = sq; }
    __syncthreads();
    s  = ss[0] + ss[1] + ss[2] + ss[3];
    sq = ssq[0] + ssq[1] + ssq[2] + ssq[3];
    float mu   = s * (1.0f / 768.0f);
    float var  = sq * (1.0f / 768.0f) - mu * mu;
    float rstd = 1.0f / sqrtf(var + 1e-5f);
    size_t o = (size_t)row * C_;
    xh[o + tid      ] = f16b((v0 - mu) * rstd * gamma[tid      ] + beta[tid      ]);
    xh[o + tid + 256] = f16b((v1 - mu) * rstd * gamma[tid + 256] + beta[tid + 256]);
    xh[o + tid + 512] = f16b((v2 - mu) * rstd * gamma[tid + 512] + beta[tid + 512]);
}

// ---------------------------------------------------------------------------
// Kernel 2: fused QKVG GEMM, 16x16x32 fp16 MFMA -- NO LDS, NO BARRIERS.
// R7: MFMA fragments load DIRECTLY from row-major global: lane l reads
// (row base+(l&15), k k0+(l>>4)*8) -- 16B contiguous per lane, 16 full 64B
// lines per fragment. Identical element mapping to the old staged path
// (verified against the LDS layout algebra), so numerics unchanged.
// Reuse via L2 (W panel read by 64 m-blocks; xh 12 MB L2-resident) and L1
// (in-block 2x wave sharing). Rationale: R0/R4/R6 showed qkvg is bound by
// the staged-tile round-trip (removing 1/3 of MFMA work saved only 11%);
// this deletes the round-trip and lets the compiler pipeline loads freely.
// ---------------------------------------------------------------------------
__global__ __launch_bounds__(256, 2) void qkvg_mfma(
    const u16* __restrict__ xh, const u16* __restrict__ wmats,
    const float* __restrict__ bq, const float* __restrict__ bk,
    const float* __restrict__ bv, const float* __restrict__ bg,
    u16* __restrict__ qh, u16* __restrict__ kh,
    u16* __restrict__ vth, u16* __restrict__ g) {
    int bx = blockIdx.x;            // m tile 0..63
    int by = blockIdx.y;            // 0..23
    int mat = by / 6;
    int n0  = (by % 6) * 128;
    int m0  = bx * 128;
    const u16* Wh = wmats + (size_t)mat * WSZ;
    const float* bias = (mat == 0) ? bq : (mat == 1) ? bk : (mat == 2) ? bv : bg;

    int tid  = threadIdx.x;
    int lane = tid & 63, wid = tid >> 6;
    int wm = (wid & 1) * 64, wn = (wid >> 1) * 64;
    int fr = lane & 15, rq = (lane >> 4) * 4;

    f32x4 acc[4][4];
    #pragma unroll
    for (int i = 0; i < 4; ++i)
        #pragma unroll
        for (int j = 0; j < 4; ++j)
            acc[i][j] = (f32x4){0.f, 0.f, 0.f, 0.f};

    const u16* Arow = xh + (size_t)(m0 + wm + fr) * 768 + (lane >> 4) * 8;
    const u16* Brow = Wh + (size_t)(n0 + wn + fr) * 768 + (lane >> 4) * 8;

    if (mat == 2) {   // v: swapped operands -> transposed (token-minor) store
        #pragma unroll 4
        for (int k0 = 0; k0 < 768; k0 += 32) {
            f16x8 fa[4], fb[4];
            #pragma unroll
            for (int i = 0; i < 4; ++i) {
                fa[i] = *(const f16x8*)(Arow + (size_t)i * 16 * 768 + k0);
                fb[i] = *(const f16x8*)(Brow + (size_t)i * 16 * 768 + k0);
            }
            #pragma unroll
            for (int mi = 0; mi < 4; ++mi)
                #pragma unroll
                for (int ni = 0; ni < 4; ++ni)
                    acc[mi][ni] = __builtin_amdgcn_mfma_f32_16x16x32_f16(fb[ni], fa[mi], acc[mi][ni], 0, 0, 0);
        }
    } else {
        #pragma unroll 4
        for (int k0 = 0; k0 < 768; k0 += 32) {
            f16x8 fa[4], fb[4];
            #pragma unroll
            for (int i = 0; i < 4; ++i) {
                fa[i] = *(const f16x8*)(Arow + (size_t)i * 16 * 768 + k0);
                fb[i] = *(const f16x8*)(Brow + (size_t)i * 16 * 768 + k0);
            }
            #pragma unroll
            for (int mi = 0; mi < 4; ++mi)
                #pragma unroll
                for (int ni = 0; ni < 4; ++ni)
                    acc[mi][ni] = __builtin_amdgcn_mfma_f32_16x16x32_f16(fa[mi], fb[ni], acc[mi][ni], 0, 0, 0);
        }
    }
    // epilogue: C/D layout col=lane&15, row=(lane>>4)*4+reg
    if (mat == 2) {
        int bb = m0 >> 10;
        #pragma unroll
        for (int mi = 0; mi < 4; ++mi) {
            int tok = m0 + wm + mi * 16 + fr;
            int tl  = tok & 1023;
            #pragma unroll
            for (int ni = 0; ni < 4; ++ni) {
                #pragma unroll
                for (int rg = 0; rg < 4; ++rg) {
                    int ch = n0 + wn + ni * 16 + rq + rg;
                    float val = acc[mi][ni][rg] + bias[ch];
                    size_t addr = ((size_t)((bb * 12 + (ch >> 6)) * 64 + (ch & 63))) * 1024 + tl;
                    vth[addr] = f16b(val);
                }
            }
        }
    } else {
        u16* oh = (mat == 0) ? qh : (mat == 1) ? kh : g;
        float scale = (mat == 0) ? 0.125f : 1.0f;
        #pragma unroll
        for (int ni = 0; ni < 4; ++ni) {
            int col = n0 + wn + ni * 16 + fr;
            float bb = bias[col];
            #pragma unroll
            for (int mi = 0; mi < 4; ++mi) {
                int row = m0 + wm + mi * 16 + rq;
                #pragma unroll
                for (int rg = 0; rg < 4; ++rg) {
                    float val = (acc[mi][ni][rg] + bb) * scale;
                    oh[(size_t)(row + rg) * 768 + col] = f16b(val);
                }
            }
        }
    }
}

// ---------------------------------------------------------------------------
// Kernel 3: MFMA flash attention, fp16 q/k/v/P. (unchanged)
// ---------------------------------------------------------------------------
__global__ __launch_bounds__(256, 3) void attn_mfma(
    const u16* __restrict__ qhg, const u16* __restrict__ khg,
    const u16* __restrict__ vthg, const u16* __restrict__ gbf,
    u16* __restrict__ yh) {
    int qt = blockIdx.x;   // 0..15
    int h  = blockIdx.y;   // 0..11
    int b  = blockIdx.z;   // 0..7
    __shared__ u16 Kh[2 * 4096], Vh[2 * 4096];
    __shared__ u16 Ps[64 * 72];
    int tid = threadIdx.x;
    int lane = tid & 63, w = tid >> 6;
    int fr = lane & 15, quad = lane >> 4, fq = quad * 8;

    size_t qbase = ((size_t)(b * 1024 + qt * 64)) * 768 + h * 64;
    size_t kbase = ((size_t)(b * 1024)) * 768 + h * 64;
    size_t vbase = ((size_t)((b * 12 + h) * 64)) * 1024;

    // Q A-fragments direct from global (loop-invariant, pre-scaled 1/8)
    f16x8 aq[2];
    #pragma unroll
    for (int kk = 0; kk < 2; ++kk)
        aq[kk] = *(const f16x8*)(qhg + qbase + (size_t)(w * 16 + fr) * 768 + kk * 32 + fq);

    float m_i[4], l_i[4];
    f32x4 Oacc[4];
    #pragma unroll
    for (int i = 0; i < 4; ++i) {
        m_i[i] = -1e30f; l_i[i] = 0.0f;
        Oacc[i] = (f32x4){0.f, 0.f, 0.f, 0.f};
    }

    int j = tid >> 5, u = tid & 31;
    int kk_ = j >> 2, nd_ = j & 3;
    size_t offK = kbase + (size_t)(nd_ * 16 + (u & 15)) * 768 + kk_ * 32 + (u >> 4) * 8;
    size_t offV = vbase + (size_t)(nd_ * 16 + (u & 15)) * 1024 + kk_ * 32 + (u >> 4) * 8;
    int lo0 = j * 512 + u * 8;

    uint4 rk0, rk1, rv0, rv1;
    #define LOADKV(ST) do { \
        size_t ok = offK + (size_t)(ST) * 49152; \
        size_t ov = offV + (size_t)(ST) * 64; \
        rk0 = *(const uint4*)(khg + ok);  rk1 = *(const uint4*)(khg + ok + 16); \
        rv0 = *(const uint4*)(vthg + ov); rv1 = *(const uint4*)(vthg + ov + 16); \
    } while (0)
    #define STOREKV(BUF) do { \
        int lb = (BUF) * 4096 + lo0; \
        *(uint4*)(Kh + lb) = rk0;  *(uint4*)(Kh + lb + 256) = rk1; \
        *(uint4*)(Vh + lb) = rv0;  *(uint4*)(Vh + lb + 256) = rv1; \
    } while (0)

    LOADKV(0);
    STOREKV(0);
    LOADKV(1);
    __syncthreads();
    int cur = 0;
    for (int st = 0; st < 16; ++st) {
        int nxt = cur ^ 1;
        STOREKV(nxt);                  // stage st+1 (garbage on last, never read)
        int s2 = (st + 2 < 16) ? (st + 2) : 0;
        LOADKV(s2);
        // S = Q K^T (wave strip 16 x 64)
        f32x4 sacc[4];
        #pragma unroll
        for (int nt = 0; nt < 4; ++nt) sacc[nt] = (f32x4){0.f, 0.f, 0.f, 0.f};
        #pragma unroll
        for (int nt = 0; nt < 4; ++nt)
            #pragma unroll
            for (int kk = 0; kk < 2; ++kk) {
                f16x8 kb = *(const f16x8*)(Kh + cur * 4096 + (kk * 4 + nt) * 512 + lane * 8);
                sacc[nt] = __builtin_amdgcn_mfma_f32_16x16x32_f16(aq[kk], kb, sacc[nt], 0, 0, 0);
            }
        // online softmax per owned row (row = w*16 + quad*4 + rg)
        #pragma unroll
        for (int rg = 0; rg < 4; ++rg) {
            float mx = fmaxf(fmaxf(sacc[0][rg], sacc[1][rg]),
                             fmaxf(sacc[2][rg], sacc[3][rg]));
            #pragma unroll
            for (int msk = 1; msk < 16; msk <<= 1) mx = fmaxf(mx, __shfl_xor(mx, msk));
            float mn = fmaxf(m_i[rg], mx);
            float al = __expf(m_i[rg] - mn);
            float p0 = __expf(sacc[0][rg] - mn);
            float p1 = __expf(sacc[1][rg] - mn);
            float p2 = __expf(sacc[2][rg] - mn);
            float p3 = __expf(sacc[3][rg] - mn);
            float rs = p0 + p1 + p2 + p3;
            #pragma unroll
            for (int msk = 1; msk < 16; msk <<= 1) rs += __shfl_xor(rs, msk);
            l_i[rg] = l_i[rg] * al + rs;
            m_i[rg] = mn;
            #pragma unroll
            for (int dn = 0; dn < 4; ++dn) Oacc[dn][rg] *= al;
            int row = w * 16 + quad * 4 + rg;
            Ps[row * 72 +  0 + fr] = f16b(p0);
            Ps[row * 72 + 16 + fr] = f16b(p1);
            Ps[row * 72 + 32 + fr] = f16b(p2);
            Ps[row * 72 + 48 + fr] = f16b(p3);
        }
        // O += P V (P wave-private rows; V in buf[cur])
        #pragma unroll
        for (int kk = 0; kk < 2; ++kk) {
            f16x8 pa = *(const f16x8*)&Ps[(w * 16 + fr) * 72 + fq + kk * 32];
            #pragma unroll
            for (int dn = 0; dn < 4; ++dn) {
                f16x8 vb = *(const f16x8*)(Vh + cur * 4096 + (kk * 4 + dn) * 512 + lane * 8);
                Oacc[dn] = __builtin_amdgcn_mfma_f32_16x16x32_f16(pa, vb, Oacc[dn], 0, 0, 0);
            }
        }
        __syncthreads();
        cur = nxt;
    }
    #undef LOADKV
    #undef STOREKV
    // epilogue: normalize, sigmoid gate, fp16 y store
    float inv[4];
    #pragma unroll
    for (int rg = 0; rg < 4; ++rg) inv[rg] = 1.0f / l_i[rg];
    #pragma unroll
    for (int dn = 0; dn < 4; ++dn) {
        int ch = h * 64 + dn * 16 + fr;
        #pragma unroll
        for (int rg = 0; rg < 4; ++rg) {
            int tok = b * 1024 + qt * 64 + w * 16 + quad * 4 + rg;
            float gv = f16f(gbf[(size_t)tok * 768 + ch]);
            float sg = 1.0f / (1.0f + __expf(-gv));
            float val = Oacc[dn][rg] * inv[rg] * sg;
            yh[(size_t)tok * 768 + ch] = f16b(val);
        }
    }
}

// ---------------------------------------------------------------------------
// Kernel 4: out = y @ Wo^T + bo -> (B, C, T) -- NO LDS, direct fragments.
// ---------------------------------------------------------------------------
__global__ __launch_bounds__(256, 2) void out_mfma(
    const u16* __restrict__ yh, const u16* __restrict__ woh,
    const float* __restrict__ bo, float* __restrict__ out) {
    int bx = blockIdx.x;   // c tile 0..5
    int by = blockIdx.y;   // t tile 0..63
    int m0 = bx * 128;     // c
    int n0 = by * 128;     // t

    int tid  = threadIdx.x;
    int lane = tid & 63, wid = tid >> 6;
    int wm = (wid & 1) * 64, wn = (wid >> 1) * 64;
    int fr = lane & 15, rq = (lane >> 4) * 4;

    f32x4 acc[4][4];
    #pragma unroll
    for (int i = 0; i < 4; ++i)
        #pragma unroll
        for (int j = 0; j < 4; ++j)
            acc[i][j] = (f32x4){0.f, 0.f, 0.f, 0.f};

    const u16* Arow = woh + (size_t)(m0 + wm + fr) * 768 + (lane >> 4) * 8;
    const u16* Brow = yh + (size_t)(n0 + wn + fr) * 768 + (lane >> 4) * 8;

    #pragma unroll 4
    for (int k0 = 0; k0 < 768; k0 += 32) {
        f16x8 fa[4], fb[4];
        #pragma unroll
        for (int i = 0; i < 4; ++i) {
            fa[i] = *(const f16x8*)(Arow + (size_t)i * 16 * 768 + k0);
            fb[i] = *(const f16x8*)(Brow + (size_t)i * 16 * 768 + k0);
        }
        #pragma unroll
        for (int mi = 0; mi < 4; ++mi)
            #pragma unroll
            for (int ni = 0; ni < 4; ++ni)
                acc[mi][ni] = __builtin_amdgcn_mfma_f32_16x16x32_f16(fa[mi], fb[ni], acc[mi][ni], 0, 0, 0);
    }
    int bb = n0 >> 10;
    #pragma unroll
    for (int ni = 0; ni < 4; ++ni) {
        int colg = n0 + wn + ni * 16 + fr;
        int tl = colg & 1023;
        #pragma unroll
        for (int mi = 0; mi < 4; ++mi) {
            int row = m0 + wm + mi * 16 + rq;
            #pragma unroll
            for (int rg = 0; rg < 4; ++rg) {
                float val = acc[mi][ni][rg] + bo[row + rg];
                out[((size_t)bb * 768 + row + rg) * 1024 + tl] = val;
            }
        }
    }
}

extern "C" void kernel_launch(void* const* d_in, const int* in_sizes, int n_in,
                              void* d_out, int out_size, void* d_ws, size_t ws_size,
                              hipStream_t stream) {
    const float* x     = (const float*)d_in[0];
    const float* Wq    = (const float*)d_in[1];
    const float* bq    = (const float*)d_in[2];
    const float* Wk    = (const float*)d_in[3];
    const float* bk    = (const float*)d_in[4];
    const float* Wv    = (const float*)d_in[5];
    const float* bv    = (const float*)d_in[6];
    const float* Wo    = (const float*)d_in[7];
    const float* bo    = (const float*)d_in[8];
    const float* Wg    = (const float*)d_in[9];
    const float* bg    = (const float*)d_in[10];
    const float* gamma = (const float*)d_in[11];
    const float* beta  = (const float*)d_in[12];
    float* out = (float*)d_out;

    // workspace (ushort, all fp16): xn|q|k|vt|g | wbuf[Wq,Wk,Wv,Wg,Wo]
    const size_t S = (size_t)BT_ * C_;
    u16* xn   = (u16*)d_ws;
    u16* qh   = xn + S;
    u16* kh   = qh + S;
    u16* vth  = kh + S;
    u16* g_bf = vth + S;
    u16* wbuf = g_bf + S;
    u16* y_h  = xn;          // alias: xn dead after qkvg

    wconv_all<<<dim3(WSZ / 1024, 5), 256, 0, stream>>>(Wq, Wk, Wv, Wg, Wo, wbuf);
    ln_kernel<<<BT_, 256, 0, stream>>>(x, gamma, beta, xn);
    qkvg_mfma<<<dim3(64, 24), 256, 0, stream>>>(xn, wbuf, bq, bk, bv, bg,
                                                qh, kh, vth, g_bf);
    attn_mfma<<<dim3(16, 12, 8), 256, 0, stream>>>(qh, kh, vth, g_bf, y_h);
    out_mfma<<<dim3(6, 64), 256, 0, stream>>>(y_h, wbuf + (size_t)4 * WSZ, bo, out);
}

// Round 8
// 321.928 us; speedup vs baseline: 1.2265x; 1.2265x over previous
//
#include <hip/hip_runtime.h>
#include <math.h>

#define B_   8
#define C_   768
#define T_   1024
#define BT_  (B_*T_)       // 8192
#define WSZ  (C_*C_)       // 589824 per weight matrix

using f16x8 = __attribute__((ext_vector_type(8))) _Float16;
using f32x4 = __attribute__((ext_vector_type(4))) float;
typedef unsigned short u16;

// ---- fp16 helpers ----
__device__ inline u16 f16b(float x) {
    _Float16 h = (_Float16)x;
    return __builtin_bit_cast(u16, h);
}
__device__ inline float f16f(u16 b) {
    return (float)__builtin_bit_cast(_Float16, b);
}

// ---------------------------------------------------------------------------
// Kernel 0: all 5 weight mats fp32 -> fp16 in one launch.
// ---------------------------------------------------------------------------
__global__ __launch_bounds__(256) void wconv_all(
    const float* __restrict__ W0, const float* __restrict__ W1,
    const float* __restrict__ W2, const float* __restrict__ W3,
    const float* __restrict__ W4, u16* __restrict__ wbuf) {
    int mat = blockIdx.y;
    const float* W = (mat == 0) ? W0 : (mat == 1) ? W1 : (mat == 2) ? W2
                   : (mat == 3) ? W3 : W4;
    u16* o = wbuf + (size_t)mat * WSZ;
    int i = (blockIdx.x * 256 + threadIdx.x) * 4;
    float4 w = *(const float4*)(W + i);
    ushort4 h;
    h.x = f16b(w.x);
    h.y = f16b(w.y);
    h.z = f16b(w.z);
    h.w = f16b(w.w);
    *(ushort4*)(o + i) = h;
}

// ---------------------------------------------------------------------------
// Kernel 1: LayerNorm with (B,C,T)->(B*T,C) transpose; writes fp16.
// ---------------------------------------------------------------------------
__global__ __launch_bounds__(256) void ln_kernel(const float* __restrict__ x,
                                                 const float* __restrict__ gamma,
                                                 const float* __restrict__ beta,
                                                 u16* __restrict__ xh) {
    int row = blockIdx.x;
    int b = row >> 10;
    int t = row & 1023;
    int tid = threadIdx.x;
    const float* xb = x + (size_t)b * C_ * T_ + t;
    float v0 = xb[(size_t)(tid      ) * T_];
    float v1 = xb[(size_t)(tid + 256) * T_];
    float v2 = xb[(size_t)(tid + 512) * T_];
    float s  = v0 + v1 + v2;
    float sq = v0 * v0 + v1 * v1 + v2 * v2;
    #pragma unroll
    for (int m = 1; m < 64; m <<= 1) {
        s  += __shfl_xor(s,  m);
        sq += __shfl_xor(sq, m);
    }
    __shared__ float ss[4], ssq[4];
    int wid = tid >> 6;
    if ((tid & 63) == 0) { ss[wid] = s; ssq[wid] = sq; }
    __syncthreads();
    s  = ss[0] + ss[1] + ss[2] + ss[3];
    sq = ssq[0] + ssq[1] + ssq[2] + ssq[3];
    float mu   = s * (1.0f / 768.0f);
    float var  = sq * (1.0f / 768.0f) - mu * mu;
    float rstd = 1.0f / sqrtf(var + 1e-5f);
    size_t o = (size_t)row * C_;
    xh[o + tid      ] = f16b((v0 - mu) * rstd * gamma[tid      ] + beta[tid      ]);
    xh[o + tid + 256] = f16b((v1 - mu) * rstd * gamma[tid + 256] + beta[tid + 256]);
    xh[o + tid + 512] = f16b((v2 - mu) * rstd * gamma[tid + 512] + beta[tid + 512]);
}

// ---------------------------------------------------------------------------
// Kernel 2: fused QKVG GEMM, 16x16x32 fp16 MFMA -- R6 structure (best of 4
// probed variants: 2-barrier TLP 130, serial gld_lds 230, DB 129/115,
// no-LDS direct 146). Single-barrier LDS double-buffer + 2-stage register
// prefetch; (256,3) to avoid the R5 spill cliff.
// ---------------------------------------------------------------------------
__global__ __launch_bounds__(256, 3) void qkvg_mfma(
    const u16* __restrict__ xh, const u16* __restrict__ wmats,
    const float* __restrict__ bq, const float* __restrict__ bk,
    const float* __restrict__ bv, const float* __restrict__ bg,
    u16* __restrict__ qh, u16* __restrict__ kh,
    u16* __restrict__ vth, u16* __restrict__ g) {
    int bx = blockIdx.x;            // m tile 0..63
    int by = blockIdx.y;            // 0..23
    int mat = by / 6;
    int n0  = (by % 6) * 128;
    int m0  = bx * 128;
    const u16* Wh = wmats + (size_t)mat * WSZ;
    const float* bias = (mat == 0) ? bq : (mat == 1) ? bk : (mat == 2) ? bv : bg;

    __shared__ __attribute__((aligned(16))) u16 Ah[2 * 4096], Bh[2 * 4096];  // 32 KB

    int tid  = threadIdx.x;
    int lane = tid & 63, wid = tid >> 6;
    int wm = (wid & 1) * 64, wn = (wid >> 1) * 64;
    int fr = lane & 15, rq = (lane >> 4) * 4;

    f32x4 acc[4][4];
    #pragma unroll
    for (int i = 0; i < 4; ++i)
        #pragma unroll
        for (int j = 0; j < 4; ++j)
            acc[i][j] = (f32x4){0.f, 0.f, 0.f, 0.f};

    int j = tid >> 5, u = tid & 31;
    size_t offA = (size_t)(m0 + j * 16 + (u & 15)) * 768 + (u >> 4) * 8;
    size_t offB = (size_t)(n0 + j * 16 + (u & 15)) * 768 + (u >> 4) * 8;
    int lo0 = j * 512 + u * 8;      // u16 units
    int ba = (wm >> 4), bb2 = (wn >> 4);

    uint4 a0, a1, c0, c1;
    #define LOADT(T) do { int kk0 = (T) * 32; \
        a0 = *(const uint4*)(xh + offA + kk0); \
        a1 = *(const uint4*)(xh + offA + kk0 + 16); \
        c0 = *(const uint4*)(Wh + offB + kk0); \
        c1 = *(const uint4*)(Wh + offB + kk0 + 16); \
    } while (0)
    #define STORET(BUF) do { int lb = (BUF) * 4096 + lo0; \
        *(uint4*)(Ah + lb) = a0;  *(uint4*)(Ah + lb + 256) = a1; \
        *(uint4*)(Bh + lb) = c0;  *(uint4*)(Bh + lb + 256) = c1; \
    } while (0)

    LOADT(0);
    STORET(0);
    LOADT(1);
    __syncthreads();
    int cur = 0;
    for (int t = 0; t < 24; ++t) {
        int nxt = cur ^ 1;
        STORET(nxt);                       // stage tile t+1 (t=23: garbage, never read)
        LOADT((t + 2 < 24) ? t + 2 : 0);   // issue tile t+2 loads
        int cb = cur * 4096;
        f16x8 fah[4], fbh[4];
        #pragma unroll
        for (int i = 0; i < 4; ++i) {
            fah[i] = *(const f16x8*)(Ah + cb + (ba + i) * 512 + lane * 8);
            fbh[i] = *(const f16x8*)(Bh + cb + (bb2 + i) * 512 + lane * 8);
        }
        if (mat == 2) {   // v: swapped operands -> transposed (token-minor) store
            #pragma unroll
            for (int mi = 0; mi < 4; ++mi)
                #pragma unroll
                for (int ni = 0; ni < 4; ++ni)
                    acc[mi][ni] = __builtin_amdgcn_mfma_f32_16x16x32_f16(fbh[ni], fah[mi], acc[mi][ni], 0, 0, 0);
        } else {
            #pragma unroll
            for (int mi = 0; mi < 4; ++mi)
                #pragma unroll
                for (int ni = 0; ni < 4; ++ni)
                    acc[mi][ni] = __builtin_amdgcn_mfma_f32_16x16x32_f16(fah[mi], fbh[ni], acc[mi][ni], 0, 0, 0);
        }
        __syncthreads();
        cur = nxt;
    }
    #undef LOADT
    #undef STORET
    // epilogue: C/D layout col=lane&15, row=(lane>>4)*4+reg
    if (mat == 2) {
        int bb = m0 >> 10;
        #pragma unroll
        for (int mi = 0; mi < 4; ++mi) {
            int tok = m0 + wm + mi * 16 + fr;
            int tl  = tok & 1023;
            #pragma unroll
            for (int ni = 0; ni < 4; ++ni) {
                #pragma unroll
                for (int rg = 0; rg < 4; ++rg) {
                    int ch = n0 + wn + ni * 16 + rq + rg;
                    float val = acc[mi][ni][rg] + bias[ch];
                    size_t addr = ((size_t)((bb * 12 + (ch >> 6)) * 64 + (ch & 63))) * 1024 + tl;
                    vth[addr] = f16b(val);
                }
            }
        }
    } else {
        u16* oh = (mat == 0) ? qh : (mat == 1) ? kh : g;
        float scale = (mat == 0) ? 0.125f : 1.0f;
        #pragma unroll
        for (int ni = 0; ni < 4; ++ni) {
            int col = n0 + wn + ni * 16 + fr;
            float bb = bias[col];
            #pragma unroll
            for (int mi = 0; mi < 4; ++mi) {
                int row = m0 + wm + mi * 16 + rq;
                #pragma unroll
                for (int rg = 0; rg < 4; ++rg) {
                    float val = (acc[mi][ni][rg] + bb) * scale;
                    oh[(size_t)(row + rg) * 768 + col] = f16b(val);
                }
            }
        }
    }
}

// ---------------------------------------------------------------------------
// Kernel 3: MFMA flash attention, fp16. R8: SWAPPED QK^T (mfma(K,Q) -> S^T,
// col = q-row). Each lane then holds 16 S-values of ONE q-row (its fr):
// row-max/sum = 15-op in-reg tree + 2 cross-quad shfl_xor (was 32 sequential
// shuffle steps for 4 rows); P-store packs 4 kv into one 8B write (4 stores
// vs 16). Rescale/normalize factors fetched with 4 width-16 shuffles.
// PV, Ps layout, Oacc orientation, epilogue indexing unchanged.
// ---------------------------------------------------------------------------
__global__ __launch_bounds__(256, 3) void attn_mfma(
    const u16* __restrict__ qhg, const u16* __restrict__ khg,
    const u16* __restrict__ vthg, const u16* __restrict__ gbf,
    u16* __restrict__ yh) {
    int qt = blockIdx.x;   // 0..15
    int h  = blockIdx.y;   // 0..11
    int b  = blockIdx.z;   // 0..7
    __shared__ u16 Kh[2 * 4096], Vh[2 * 4096];
    __shared__ u16 Ps[64 * 72];
    int tid = threadIdx.x;
    int lane = tid & 63, w = tid >> 6;
    int fr = lane & 15, quad = lane >> 4, fq = quad * 8;

    size_t qbase = ((size_t)(b * 1024 + qt * 64)) * 768 + h * 64;
    size_t kbase = ((size_t)(b * 1024)) * 768 + h * 64;
    size_t vbase = ((size_t)((b * 12 + h) * 64)) * 1024;

    // Q B-fragments direct from global (loop-invariant, pre-scaled 1/8)
    f16x8 aq[2];
    #pragma unroll
    for (int kk = 0; kk < 2; ++kk)
        aq[kk] = *(const f16x8*)(qhg + qbase + (size_t)(w * 16 + fr) * 768 + kk * 32 + fq);

    float m_s = -1e30f, l_s = 0.0f;    // stats for row q = w*16 + fr
    f32x4 Oacc[4];
    #pragma unroll
    for (int i = 0; i < 4; ++i) Oacc[i] = (f32x4){0.f, 0.f, 0.f, 0.f};

    int j = tid >> 5, u = tid & 31;
    int kk_ = j >> 2, nd_ = j & 3;
    size_t offK = kbase + (size_t)(nd_ * 16 + (u & 15)) * 768 + kk_ * 32 + (u >> 4) * 8;
    size_t offV = vbase + (size_t)(nd_ * 16 + (u & 15)) * 1024 + kk_ * 32 + (u >> 4) * 8;
    int lo0 = j * 512 + u * 8;

    uint4 rk0, rk1, rv0, rv1;
    #define LOADKV(ST) do { \
        size_t ok = offK + (size_t)(ST) * 49152; \
        size_t ov = offV + (size_t)(ST) * 64; \
        rk0 = *(const uint4*)(khg + ok);  rk1 = *(const uint4*)(khg + ok + 16); \
        rv0 = *(const uint4*)(vthg + ov); rv1 = *(const uint4*)(vthg + ov + 16); \
    } while (0)
    #define STOREKV(BUF) do { \
        int lb = (BUF) * 4096 + lo0; \
        *(uint4*)(Kh + lb) = rk0;  *(uint4*)(Kh + lb + 256) = rk1; \
        *(uint4*)(Vh + lb) = rv0;  *(uint4*)(Vh + lb + 256) = rv1; \
    } while (0)

    LOADKV(0);
    STOREKV(0);
    LOADKV(1);
    __syncthreads();
    int cur = 0;
    for (int st = 0; st < 16; ++st) {
        int nxt = cur ^ 1;
        STOREKV(nxt);                  // stage st+1 (garbage on last, never read)
        int s2 = (st + 2 < 16) ? (st + 2) : 0;
        LOADKV(s2);
        // S^T = K Q^T: sacc[nt][rg] = S[q=w*16+fr][kv = nt*16 + quad*4 + rg]
        f32x4 sacc[4];
        #pragma unroll
        for (int nt = 0; nt < 4; ++nt) sacc[nt] = (f32x4){0.f, 0.f, 0.f, 0.f};
        #pragma unroll
        for (int nt = 0; nt < 4; ++nt)
            #pragma unroll
            for (int kk = 0; kk < 2; ++kk) {
                f16x8 kb = *(const f16x8*)(Kh + cur * 4096 + (kk * 4 + nt) * 512 + lane * 8);
                sacc[nt] = __builtin_amdgcn_mfma_f32_16x16x32_f16(kb, aq[kk], sacc[nt], 0, 0, 0);
            }
        // in-register softmax for row q (lane-local 16 values + 2 shuffles)
        float mx = -1e30f;
        #pragma unroll
        for (int nt = 0; nt < 4; ++nt)
            #pragma unroll
            for (int rg = 0; rg < 4; ++rg) mx = fmaxf(mx, sacc[nt][rg]);
        mx = fmaxf(mx, __shfl_xor(mx, 16));
        mx = fmaxf(mx, __shfl_xor(mx, 32));
        float mn = fmaxf(m_s, mx);
        float al = __expf(m_s - mn);
        m_s = mn;
        float rs = 0.0f;
        #pragma unroll
        for (int nt = 0; nt < 4; ++nt)
            #pragma unroll
            for (int rg = 0; rg < 4; ++rg) {
                float p = __expf(sacc[nt][rg] - mn);
                sacc[nt][rg] = p;
                rs += p;
            }
        rs += __shfl_xor(rs, 16);
        rs += __shfl_xor(rs, 32);
        l_s = l_s * al + rs;
        // store P row: 4x 8B packed writes (kv = nt*16 + quad*4 + 0..3)
        int prow = (w * 16 + fr) * 72;
        #pragma unroll
        for (int nt = 0; nt < 4; ++nt) {
            ushort4 hp;
            hp.x = f16b(sacc[nt][0]);
            hp.y = f16b(sacc[nt][1]);
            hp.z = f16b(sacc[nt][2]);
            hp.w = f16b(sacc[nt][3]);
            *(ushort4*)&Ps[prow + nt * 16 + quad * 4] = hp;
        }
        // rescale Oacc (lane's O rows are quad*4+rg; al lives in fr-lanes)
        float alr[4];
        #pragma unroll
        for (int rg = 0; rg < 4; ++rg) alr[rg] = __shfl(al, quad * 4 + rg, 16);
        #pragma unroll
        for (int dn = 0; dn < 4; ++dn)
            #pragma unroll
            for (int rg = 0; rg < 4; ++rg) Oacc[dn][rg] *= alr[rg];
        // O += P V (P wave-private rows; V in buf[cur])
        #pragma unroll
        for (int kk = 0; kk < 2; ++kk) {
            f16x8 pa = *(const f16x8*)&Ps[(w * 16 + fr) * 72 + fq + kk * 32];
            #pragma unroll
            for (int dn = 0; dn < 4; ++dn) {
                f16x8 vb = *(const f16x8*)(Vh + cur * 4096 + (kk * 4 + dn) * 512 + lane * 8);
                Oacc[dn] = __builtin_amdgcn_mfma_f32_16x16x32_f16(pa, vb, Oacc[dn], 0, 0, 0);
            }
        }
        __syncthreads();
        cur = nxt;
    }
    #undef LOADKV
    #undef STOREKV
    // epilogue: normalize (fetch l for rows quad*4+rg), sigmoid gate, store
    float inv[4];
    #pragma unroll
    for (int rg = 0; rg < 4; ++rg) inv[rg] = 1.0f / __shfl(l_s, quad * 4 + rg, 16);
    #pragma unroll
    for (int dn = 0; dn < 4; ++dn) {
        int ch = h * 64 + dn * 16 + fr;
        #pragma unroll
        for (int rg = 0; rg < 4; ++rg) {
            int tok = b * 1024 + qt * 64 + w * 16 + quad * 4 + rg;
            float gv = f16f(gbf[(size_t)tok * 768 + ch]);
            float sg = 1.0f / (1.0f + __expf(-gv));
            float val = Oacc[dn][rg] * inv[rg] * sg;
            yh[(size_t)tok * 768 + ch] = f16b(val);
        }
    }
}

// ---------------------------------------------------------------------------
// Kernel 4: out = y @ Wo^T + bo -> (B, C, T), single fp16 MFMA.
// R6 DB structure.
// ---------------------------------------------------------------------------
__global__ __launch_bounds__(256, 3) void out_mfma(
    const u16* __restrict__ yh, const u16* __restrict__ woh,
    const float* __restrict__ bo, float* __restrict__ out) {
    int bx = blockIdx.x;   // c tile 0..5
    int by = blockIdx.y;   // t tile 0..63
    int m0 = bx * 128;     // c
    int n0 = by * 128;     // t

    __shared__ __attribute__((aligned(16))) u16 Ah[2 * 4096], Bh[2 * 4096];  // 32 KB

    int tid  = threadIdx.x;
    int lane = tid & 63, wid = tid >> 6;
    int wm = (wid & 1) * 64, wn = (wid >> 1) * 64;
    int fr = lane & 15, rq = (lane >> 4) * 4;

    f32x4 acc[4][4];
    #pragma unroll
    for (int i = 0; i < 4; ++i)
        #pragma unroll
        for (int j = 0; j < 4; ++j)
            acc[i][j] = (f32x4){0.f, 0.f, 0.f, 0.f};

    int j = tid >> 5, u = tid & 31;
    size_t offA = (size_t)(m0 + j * 16 + (u & 15)) * 768 + (u >> 4) * 8;
    size_t offB = (size_t)(n0 + j * 16 + (u & 15)) * 768 + (u >> 4) * 8;
    int lo0 = j * 512 + u * 8;
    int ba = (wm >> 4), bb2 = (wn >> 4);

    uint4 a0, a1, c0, c1;
    #define LOADT(T) do { int kk0 = (T) * 32; \
        a0 = *(const uint4*)(woh + offA + kk0); \
        a1 = *(const uint4*)(woh + offA + kk0 + 16); \
        c0 = *(const uint4*)(yh + offB + kk0); \
        c1 = *(const uint4*)(yh + offB + kk0 + 16); \
    } while (0)
    #define STORET(BUF) do { int lb = (BUF) * 4096 + lo0; \
        *(uint4*)(Ah + lb) = a0;  *(uint4*)(Ah + lb + 256) = a1; \
        *(uint4*)(Bh + lb) = c0;  *(uint4*)(Bh + lb + 256) = c1; \
    } while (0)

    LOADT(0);
    STORET(0);
    LOADT(1);
    __syncthreads();
    int cur = 0;
    for (int t = 0; t < 24; ++t) {
        int nxt = cur ^ 1;
        STORET(nxt);
        LOADT((t + 2 < 24) ? t + 2 : 0);
        int cb = cur * 4096;
        f16x8 fah[4], fbh[4];
        #pragma unroll
        for (int i = 0; i < 4; ++i) {
            fah[i] = *(const f16x8*)(Ah + cb + (ba + i) * 512 + lane * 8);
            fbh[i] = *(const f16x8*)(Bh + cb + (bb2 + i) * 512 + lane * 8);
        }
        #pragma unroll
        for (int mi = 0; mi < 4; ++mi)
            #pragma unroll
            for (int ni = 0; ni < 4; ++ni)
                acc[mi][ni] = __builtin_amdgcn_mfma_f32_16x16x32_f16(fah[mi], fbh[ni], acc[mi][ni], 0, 0, 0);
        __syncthreads();
        cur = nxt;
    }
    #undef LOADT
    #undef STORET
    int bb = n0 >> 10;
    #pragma unroll
    for (int ni = 0; ni < 4; ++ni) {
        int colg = n0 + wn + ni * 16 + fr;
        int tl = colg & 1023;
        #pragma unroll
        for (int mi = 0; mi < 4; ++mi) {
            int row = m0 + wm + mi * 16 + rq;
            #pragma unroll
            for (int rg = 0; rg < 4; ++rg) {
                float val = acc[mi][ni][rg] + bo[row + rg];
                out[((size_t)bb * 768 + row + rg) * 1024 + tl] = val;
            }
        }
    }
}

extern "C" void kernel_launch(void* const* d_in, const int* in_sizes, int n_in,
                              void* d_out, int out_size, void* d_ws, size_t ws_size,
                              hipStream_t stream) {
    const float* x     = (const float*)d_in[0];
    const float* Wq    = (const float*)d_in[1];
    const float* bq    = (const float*)d_in[2];
    const float* Wk    = (const float*)d_in[3];
    const float* bk    = (const float*)d_in[4];
    const float* Wv    = (const float*)d_in[5];
    const float* bv    = (const float*)d_in[6];
    const float* Wo    = (const float*)d_in[7];
    const float* bo    = (const float*)d_in[8];
    const float* Wg    = (const float*)d_in[9];
    const float* bg    = (const float*)d_in[10];
    const float* gamma = (const float*)d_in[11];
    const float* beta  = (const float*)d_in[12];
    float* out = (float*)d_out;

    // workspace (ushort, all fp16): xn|q|k|vt|g | wbuf[Wq,Wk,Wv,Wg,Wo]
    const size_t S = (size_t)BT_ * C_;
    u16* xn   = (u16*)d_ws;
    u16* qh   = xn + S;
    u16* kh   = qh + S;
    u16* vth  = kh + S;
    u16* g_bf = vth + S;
    u16* wbuf = g_bf + S;
    u16* y_h  = xn;          // alias: xn dead after qkvg

    wconv_all<<<dim3(WSZ / 1024, 5), 256, 0, stream>>>(Wq, Wk, Wv, Wg, Wo, wbuf);
    ln_kernel<<<BT_, 256, 0, stream>>>(x, gamma, beta, xn);
    qkvg_mfma<<<dim3(64, 24), 256, 0, stream>>>(xn, wbuf, bq, bk, bv, bg,
                                                qh, kh, vth, g_bf);
    attn_mfma<<<dim3(16, 12, 8), 256, 0, stream>>>(qh, kh, vth, g_bf, y_h);
    out_mfma<<<dim3(6, 64), 256, 0, stream>>>(y_h, wbuf + (size_t)4 * WSZ, bo, out);
}

// Round 9
// 318.352 us; speedup vs baseline: 1.2403x; 1.0112x over previous
//
#include <hip/hip_runtime.h>
#include <math.h>

#define B_   8
#define C_   768
#define T_   1024
#define BT_  (B_*T_)       // 8192
#define WSZ  (C_*C_)       // 589824 per weight matrix

using f16x8 = __attribute__((ext_vector_type(8))) _Float16;
using f32x4 = __attribute__((ext_vector_type(4))) float;
typedef unsigned short u16;

// ---- fp16 helpers ----
__device__ inline u16 f16b(float x) {
    _Float16 h = (_Float16)x;
    return __builtin_bit_cast(u16, h);
}
__device__ inline float f16f(u16 b) {
    return (float)__builtin_bit_cast(_Float16, b);
}

// ---------------------------------------------------------------------------
// Kernel 0: all 5 weight mats fp32 -> fp16 in one launch.
// ---------------------------------------------------------------------------
__global__ __launch_bounds__(256) void wconv_all(
    const float* __restrict__ W0, const float* __restrict__ W1,
    const float* __restrict__ W2, const float* __restrict__ W3,
    const float* __restrict__ W4, u16* __restrict__ wbuf) {
    int mat = blockIdx.y;
    const float* W = (mat == 0) ? W0 : (mat == 1) ? W1 : (mat == 2) ? W2
                   : (mat == 3) ? W3 : W4;
    u16* o = wbuf + (size_t)mat * WSZ;
    int i = (blockIdx.x * 256 + threadIdx.x) * 4;
    float4 w = *(const float4*)(W + i);
    ushort4 h;
    h.x = f16b(w.x);
    h.y = f16b(w.y);
    h.z = f16b(w.z);
    h.w = f16b(w.w);
    *(ushort4*)(o + i) = h;
}

// ---------------------------------------------------------------------------
// Kernel 1: LayerNorm, R9 rewrite: 16-token tile per block, fully-coalesced
// fp32 loads (old version read x at stride 4KB -- every lane its own line),
// LDS transpose, coalesced fp16 stores.
// grid (64, 8): t-tile x b. Thread (cg=tid>>4, tx=tid&15): handles c=i*16+cg
// for t = t0+tx. A wave's 64 lanes = 4 c x 16 t = 4 fully-used 64B lines.
// ---------------------------------------------------------------------------
__global__ __launch_bounds__(256) void ln_kernel(const float* __restrict__ x,
                                                 const float* __restrict__ gamma,
                                                 const float* __restrict__ beta,
                                                 u16* __restrict__ xh) {
    int b = blockIdx.y;
    int t0 = blockIdx.x * 16;
    int tid = threadIdx.x;
    int tx = tid & 15;          // t offset
    int cg = tid >> 4;          // c group 0..15
    const float* xb = x + (size_t)b * C_ * T_ + t0 + tx;

    float v[48];
    float s = 0.f, sq = 0.f;
    #pragma unroll
    for (int i = 0; i < 48; ++i) {
        float val = xb[(size_t)(i * 16 + cg) * T_];
        v[i] = val; s += val; sq += val * val;
    }
    __shared__ float rs_[16][16], rq_[16][16];   // [cg][tx]
    rs_[cg][tx] = s;
    rq_[cg][tx] = sq;
    __syncthreads();
    __shared__ float mu_[16], rstd_[16];
    if (tid < 16) {
        float S = 0.f, Q = 0.f;
        #pragma unroll
        for (int k = 0; k < 16; ++k) { S += rs_[k][tid]; Q += rq_[k][tid]; }
        float mu = S * (1.0f / 768.0f);
        float var = Q * (1.0f / 768.0f) - mu * mu;
        mu_[tid] = mu;
        rstd_[tid] = 1.0f / sqrtf(var + 1e-5f);
    }
    __syncthreads();
    float mu = mu_[tx], rstd = rstd_[tx];
    __shared__ u16 Lt[16][776];                  // +8 u16 pad: kills write conflicts
    #pragma unroll
    for (int i = 0; i < 48; ++i) {
        int c = i * 16 + cg;
        Lt[tx][c] = f16b((v[i] - mu) * rstd * gamma[c] + beta[c]);
    }
    __syncthreads();
    size_t obase = ((size_t)b * 1024 + t0) * C_;
    #pragma unroll
    for (int st = 0; st < 12; ++st) {
        int idx = st * 256 + tid;
        int t = idx / 192, c4 = idx % 192;
        *(ushort4*)(xh + obase + (size_t)t * C_ + c4 * 4) = *(ushort4*)&Lt[t][c4 * 4];
    }
}

// ---------------------------------------------------------------------------
// Kernel 2: fused QKVG GEMM, fp16 MFMA. R9 HYBRID:
//  - B (weights) staged via the proven R6 single-barrier LDS double-buffer
//    + 2-stage reg prefetch (latency reservoir + cross-wave reuse);
//  - A (xn) fragments DIRECT from global (R7-verified mapping) with 2-deep
//    register prefetch issued after the MFMA cluster (covered by barrier +
//    next body).
// Rationale: R8 analysis -- 192 B/thread-iter of LDS traffic caps MfmaUtil
// at ~13.5% (measured 14%). Halving to 96 B lifts the cap to ~27%.
// (256,2): VGPR cap 128 (gfx950: 256/waves-per-EU; (256,3)=85 would spill
// the ~120 live regs). fb read ni-outer, one live at a time.
// ---------------------------------------------------------------------------
__global__ __launch_bounds__(256, 2) void qkvg_mfma(
    const u16* __restrict__ xh, const u16* __restrict__ wmats,
    const float* __restrict__ bq, const float* __restrict__ bk,
    const float* __restrict__ bv, const float* __restrict__ bg,
    u16* __restrict__ qh, u16* __restrict__ kh,
    u16* __restrict__ vth, u16* __restrict__ g) {
    int bx = blockIdx.x;            // m tile 0..63
    int by = blockIdx.y;            // 0..23
    int mat = by / 6;
    int n0  = (by % 6) * 128;
    int m0  = bx * 128;
    const u16* Wh = wmats + (size_t)mat * WSZ;
    const float* bias = (mat == 0) ? bq : (mat == 1) ? bk : (mat == 2) ? bv : bg;

    __shared__ __attribute__((aligned(16))) u16 Bh[2 * 4096];   // 16 KB

    int tid  = threadIdx.x;
    int lane = tid & 63, wid = tid >> 6;
    int wm = (wid & 1) * 64, wn = (wid >> 1) * 64;
    int fr = lane & 15, rq = (lane >> 4) * 4;

    f32x4 acc[4][4];
    #pragma unroll
    for (int i = 0; i < 4; ++i)
        #pragma unroll
        for (int j = 0; j < 4; ++j)
            acc[i][j] = (f32x4){0.f, 0.f, 0.f, 0.f};

    int j = tid >> 5, u = tid & 31;
    size_t offB = (size_t)(n0 + j * 16 + (u & 15)) * 768 + (u >> 4) * 8;
    int lo0 = j * 512 + u * 8;      // u16 units
    int bb2 = (wn >> 4);

    const u16* Arow = xh + (size_t)(m0 + wm + fr) * 768 + (lane >> 4) * 8;

    uint4 c0, c1;
    f16x8 aA[4], aB[4];
    #define LOADB(T) do { int kk0 = (T) * 32; \
        c0 = *(const uint4*)(Wh + offB + kk0); \
        c1 = *(const uint4*)(Wh + offB + kk0 + 16); \
    } while (0)
    #define STOREB(BUF) do { int lb = (BUF) * 4096 + lo0; \
        *(uint4*)(Bh + lb) = c0;  *(uint4*)(Bh + lb + 256) = c1; \
    } while (0)
    #define LOADA(dst, T) do { int kk0 = (T) * 32; \
        dst[0] = *(const f16x8*)(Arow + kk0); \
        dst[1] = *(const f16x8*)(Arow + 12288 + kk0); \
        dst[2] = *(const f16x8*)(Arow + 24576 + kk0); \
        dst[3] = *(const f16x8*)(Arow + 36864 + kk0); \
    } while (0)
    #define BODY(AREG, T) do { \
        STOREB(cur ^ 1); \
        LOADB(((T) + 2 < 24) ? (T) + 2 : 0); \
        int cb = cur * 4096; \
        if (mat == 2) { \
            _Pragma("unroll") \
            for (int ni = 0; ni < 4; ++ni) { \
                f16x8 fb = *(const f16x8*)(Bh + cb + (bb2 + ni) * 512 + lane * 8); \
                _Pragma("unroll") \
                for (int mi = 0; mi < 4; ++mi) \
                    acc[mi][ni] = __builtin_amdgcn_mfma_f32_16x16x32_f16(fb, AREG[mi], acc[mi][ni], 0, 0, 0); \
            } \
        } else { \
            _Pragma("unroll") \
            for (int ni = 0; ni < 4; ++ni) { \
                f16x8 fb = *(const f16x8*)(Bh + cb + (bb2 + ni) * 512 + lane * 8); \
                _Pragma("unroll") \
                for (int mi = 0; mi < 4; ++mi) \
                    acc[mi][ni] = __builtin_amdgcn_mfma_f32_16x16x32_f16(AREG[mi], fb, acc[mi][ni], 0, 0, 0); \
            } \
        } \
        LOADA(AREG, ((T) + 2 < 24) ? (T) + 2 : 0); \
        __syncthreads(); \
        cur ^= 1; \
    } while (0)

    LOADB(0);
    STOREB(0);
    LOADB(1);
    LOADA(aA, 0);
    LOADA(aB, 1);
    __syncthreads();
    int cur = 0;
    for (int t = 0; t < 24; t += 2) {
        BODY(aA, t);
        BODY(aB, t + 1);
    }
    #undef LOADB
    #undef STOREB
    #undef LOADA
    #undef BODY
    // epilogue: C/D layout col=lane&15, row=(lane>>4)*4+reg
    if (mat == 2) {
        int bb = m0 >> 10;
        #pragma unroll
        for (int mi = 0; mi < 4; ++mi) {
            int tok = m0 + wm + mi * 16 + fr;
            int tl  = tok & 1023;
            #pragma unroll
            for (int ni = 0; ni < 4; ++ni) {
                #pragma unroll
                for (int rg = 0; rg < 4; ++rg) {
                    int ch = n0 + wn + ni * 16 + rq + rg;
                    float val = acc[mi][ni][rg] + bias[ch];
                    size_t addr = ((size_t)((bb * 12 + (ch >> 6)) * 64 + (ch & 63))) * 1024 + tl;
                    vth[addr] = f16b(val);
                }
            }
        }
    } else {
        u16* oh = (mat == 0) ? qh : (mat == 1) ? kh : g;
        float scale = (mat == 0) ? 0.125f : 1.0f;
        #pragma unroll
        for (int ni = 0; ni < 4; ++ni) {
            int col = n0 + wn + ni * 16 + fr;
            float bb = bias[col];
            #pragma unroll
            for (int mi = 0; mi < 4; ++mi) {
                int row = m0 + wm + mi * 16 + rq;
                #pragma unroll
                for (int rg = 0; rg < 4; ++rg) {
                    float val = (acc[mi][ni][rg] + bb) * scale;
                    oh[(size_t)(row + rg) * 768 + col] = f16b(val);
                }
            }
        }
    }
}

// ---------------------------------------------------------------------------
// Kernel 3: MFMA flash attention, fp16, swapped QK^T (R8, unchanged).
// ---------------------------------------------------------------------------
__global__ __launch_bounds__(256, 3) void attn_mfma(
    const u16* __restrict__ qhg, const u16* __restrict__ khg,
    const u16* __restrict__ vthg, const u16* __restrict__ gbf,
    u16* __restrict__ yh) {
    int qt = blockIdx.x;   // 0..15
    int h  = blockIdx.y;   // 0..11
    int b  = blockIdx.z;   // 0..7
    __shared__ u16 Kh[2 * 4096], Vh[2 * 4096];
    __shared__ u16 Ps[64 * 72];
    int tid = threadIdx.x;
    int lane = tid & 63, w = tid >> 6;
    int fr = lane & 15, quad = lane >> 4, fq = quad * 8;

    size_t qbase = ((size_t)(b * 1024 + qt * 64)) * 768 + h * 64;
    size_t kbase = ((size_t)(b * 1024)) * 768 + h * 64;
    size_t vbase = ((size_t)((b * 12 + h) * 64)) * 1024;

    f16x8 aq[2];
    #pragma unroll
    for (int kk = 0; kk < 2; ++kk)
        aq[kk] = *(const f16x8*)(qhg + qbase + (size_t)(w * 16 + fr) * 768 + kk * 32 + fq);

    float m_s = -1e30f, l_s = 0.0f;    // stats for row q = w*16 + fr
    f32x4 Oacc[4];
    #pragma unroll
    for (int i = 0; i < 4; ++i) Oacc[i] = (f32x4){0.f, 0.f, 0.f, 0.f};

    int j = tid >> 5, u = tid & 31;
    int kk_ = j >> 2, nd_ = j & 3;
    size_t offK = kbase + (size_t)(nd_ * 16 + (u & 15)) * 768 + kk_ * 32 + (u >> 4) * 8;
    size_t offV = vbase + (size_t)(nd_ * 16 + (u & 15)) * 1024 + kk_ * 32 + (u >> 4) * 8;
    int lo0 = j * 512 + u * 8;

    uint4 rk0, rk1, rv0, rv1;
    #define LOADKV(ST) do { \
        size_t ok = offK + (size_t)(ST) * 49152; \
        size_t ov = offV + (size_t)(ST) * 64; \
        rk0 = *(const uint4*)(khg + ok);  rk1 = *(const uint4*)(khg + ok + 16); \
        rv0 = *(const uint4*)(vthg + ov); rv1 = *(const uint4*)(vthg + ov + 16); \
    } while (0)
    #define STOREKV(BUF) do { \
        int lb = (BUF) * 4096 + lo0; \
        *(uint4*)(Kh + lb) = rk0;  *(uint4*)(Kh + lb + 256) = rk1; \
        *(uint4*)(Vh + lb) = rv0;  *(uint4*)(Vh + lb + 256) = rv1; \
    } while (0)

    LOADKV(0);
    STOREKV(0);
    LOADKV(1);
    __syncthreads();
    int cur = 0;
    for (int st = 0; st < 16; ++st) {
        int nxt = cur ^ 1;
        STOREKV(nxt);
        int s2 = (st + 2 < 16) ? (st + 2) : 0;
        LOADKV(s2);
        // S^T = K Q^T: sacc[nt][rg] = S[q=w*16+fr][kv = nt*16 + quad*4 + rg]
        f32x4 sacc[4];
        #pragma unroll
        for (int nt = 0; nt < 4; ++nt) sacc[nt] = (f32x4){0.f, 0.f, 0.f, 0.f};
        #pragma unroll
        for (int nt = 0; nt < 4; ++nt)
            #pragma unroll
            for (int kk = 0; kk < 2; ++kk) {
                f16x8 kb = *(const f16x8*)(Kh + cur * 4096 + (kk * 4 + nt) * 512 + lane * 8);
                sacc[nt] = __builtin_amdgcn_mfma_f32_16x16x32_f16(kb, aq[kk], sacc[nt], 0, 0, 0);
            }
        // in-register softmax for row q
        float mx = -1e30f;
        #pragma unroll
        for (int nt = 0; nt < 4; ++nt)
            #pragma unroll
            for (int rg = 0; rg < 4; ++rg) mx = fmaxf(mx, sacc[nt][rg]);
        mx = fmaxf(mx, __shfl_xor(mx, 16));
        mx = fmaxf(mx, __shfl_xor(mx, 32));
        float mn = fmaxf(m_s, mx);
        float al = __expf(m_s - mn);
        m_s = mn;
        float rs = 0.0f;
        #pragma unroll
        for (int nt = 0; nt < 4; ++nt)
            #pragma unroll
            for (int rg = 0; rg < 4; ++rg) {
                float p = __expf(sacc[nt][rg] - mn);
                sacc[nt][rg] = p;
                rs += p;
            }
        rs += __shfl_xor(rs, 16);
        rs += __shfl_xor(rs, 32);
        l_s = l_s * al + rs;
        // store P row: 4x 8B packed writes
        int prow = (w * 16 + fr) * 72;
        #pragma unroll
        for (int nt = 0; nt < 4; ++nt) {
            ushort4 hp;
            hp.x = f16b(sacc[nt][0]);
            hp.y = f16b(sacc[nt][1]);
            hp.z = f16b(sacc[nt][2]);
            hp.w = f16b(sacc[nt][3]);
            *(ushort4*)&Ps[prow + nt * 16 + quad * 4] = hp;
        }
        // rescale Oacc
        float alr[4];
        #pragma unroll
        for (int rg = 0; rg < 4; ++rg) alr[rg] = __shfl(al, quad * 4 + rg, 16);
        #pragma unroll
        for (int dn = 0; dn < 4; ++dn)
            #pragma unroll
            for (int rg = 0; rg < 4; ++rg) Oacc[dn][rg] *= alr[rg];
        // O += P V
        #pragma unroll
        for (int kk = 0; kk < 2; ++kk) {
            f16x8 pa = *(const f16x8*)&Ps[(w * 16 + fr) * 72 + fq + kk * 32];
            #pragma unroll
            for (int dn = 0; dn < 4; ++dn) {
                f16x8 vb = *(const f16x8*)(Vh + cur * 4096 + (kk * 4 + dn) * 512 + lane * 8);
                Oacc[dn] = __builtin_amdgcn_mfma_f32_16x16x32_f16(pa, vb, Oacc[dn], 0, 0, 0);
            }
        }
        __syncthreads();
        cur = nxt;
    }
    #undef LOADKV
    #undef STOREKV
    float inv[4];
    #pragma unroll
    for (int rg = 0; rg < 4; ++rg) inv[rg] = 1.0f / __shfl(l_s, quad * 4 + rg, 16);
    #pragma unroll
    for (int dn = 0; dn < 4; ++dn) {
        int ch = h * 64 + dn * 16 + fr;
        #pragma unroll
        for (int rg = 0; rg < 4; ++rg) {
            int tok = b * 1024 + qt * 64 + w * 16 + quad * 4 + rg;
            float gv = f16f(gbf[(size_t)tok * 768 + ch]);
            float sg = 1.0f / (1.0f + __expf(-gv));
            float val = Oacc[dn][rg] * inv[rg] * sg;
            yh[(size_t)tok * 768 + ch] = f16b(val);
        }
    }
}

// ---------------------------------------------------------------------------
// Kernel 4: out = y @ Wo^T + bo -> (B, C, T). R9 hybrid: B (yh) staged DB,
// A (Wo) direct-from-global with 2-deep reg prefetch. Same reasoning as qkvg.
// ---------------------------------------------------------------------------
__global__ __launch_bounds__(256, 2) void out_mfma(
    const u16* __restrict__ yh, const u16* __restrict__ woh,
    const float* __restrict__ bo, float* __restrict__ out) {
    int bx = blockIdx.x;   // c tile 0..5
    int by = blockIdx.y;   // t tile 0..63
    int m0 = bx * 128;     // c
    int n0 = by * 128;     // t

    __shared__ __attribute__((aligned(16))) u16 Bh[2 * 4096];   // 16 KB

    int tid  = threadIdx.x;
    int lane = tid & 63, wid = tid >> 6;
    int wm = (wid & 1) * 64, wn = (wid >> 1) * 64;
    int fr = lane & 15, rq = (lane >> 4) * 4;

    f32x4 acc[4][4];
    #pragma unroll
    for (int i = 0; i < 4; ++i)
        #pragma unroll
        for (int j = 0; j < 4; ++j)
            acc[i][j] = (f32x4){0.f, 0.f, 0.f, 0.f};

    int j = tid >> 5, u = tid & 31;
    size_t offB = (size_t)(n0 + j * 16 + (u & 15)) * 768 + (u >> 4) * 8;
    int lo0 = j * 512 + u * 8;
    int bb2 = (wn >> 4);

    const u16* Arow = woh + (size_t)(m0 + wm + fr) * 768 + (lane >> 4) * 8;

    uint4 c0, c1;
    f16x8 aA[4], aB[4];
    #define LOADB(T) do { int kk0 = (T) * 32; \
        c0 = *(const uint4*)(yh + offB + kk0); \
        c1 = *(const uint4*)(yh + offB + kk0 + 16); \
    } while (0)
    #define STOREB(BUF) do { int lb = (BUF) * 4096 + lo0; \
        *(uint4*)(Bh + lb) = c0;  *(uint4*)(Bh + lb + 256) = c1; \
    } while (0)
    #define LOADA(dst, T) do { int kk0 = (T) * 32; \
        dst[0] = *(const f16x8*)(Arow + kk0); \
        dst[1] = *(const f16x8*)(Arow + 12288 + kk0); \
        dst[2] = *(const f16x8*)(Arow + 24576 + kk0); \
        dst[3] = *(const f16x8*)(Arow + 36864 + kk0); \
    } while (0)
    #define BODY(AREG, T) do { \
        STOREB(cur ^ 1); \
        LOADB(((T) + 2 < 24) ? (T) + 2 : 0); \
        int cb = cur * 4096; \
        _Pragma("unroll") \
        for (int ni = 0; ni < 4; ++ni) { \
            f16x8 fb = *(const f16x8*)(Bh + cb + (bb2 + ni) * 512 + lane * 8); \
            _Pragma("unroll") \
            for (int mi = 0; mi < 4; ++mi) \
                acc[mi][ni] = __builtin_amdgcn_mfma_f32_16x16x32_f16(AREG[mi], fb, acc[mi][ni], 0, 0, 0); \
        } \
        LOADA(AREG, ((T) + 2 < 24) ? (T) + 2 : 0); \
        __syncthreads(); \
        cur ^= 1; \
    } while (0)

    LOADB(0);
    STOREB(0);
    LOADB(1);
    LOADA(aA, 0);
    LOADA(aB, 1);
    __syncthreads();
    int cur = 0;
    for (int t = 0; t < 24; t += 2) {
        BODY(aA, t);
        BODY(aB, t + 1);
    }
    #undef LOADB
    #undef STOREB
    #undef LOADA
    #undef BODY
    int bb = n0 >> 10;
    #pragma unroll
    for (int ni = 0; ni < 4; ++ni) {
        int colg = n0 + wn + ni * 16 + fr;
        int tl = colg & 1023;
        #pragma unroll
        for (int mi = 0; mi < 4; ++mi) {
            int row = m0 + wm + mi * 16 + rq;
            #pragma unroll
            for (int rg = 0; rg < 4; ++rg) {
                float val = acc[mi][ni][rg] + bo[row + rg];
                out[((size_t)bb * 768 + row + rg) * 1024 + tl] = val;
            }
        }
    }
}

extern "C" void kernel_launch(void* const* d_in, const int* in_sizes, int n_in,
                              void* d_out, int out_size, void* d_ws, size_t ws_size,
                              hipStream_t stream) {
    const float* x     = (const float*)d_in[0];
    const float* Wq    = (const float*)d_in[1];
    const float* bq    = (const float*)d_in[2];
    const float* Wk    = (const float*)d_in[3];
    const float* bk    = (const float*)d_in[4];
    const float* Wv    = (const float*)d_in[5];
    const float* bv    = (const float*)d_in[6];
    const float* Wo    = (const float*)d_in[7];
    const float* bo    = (const float*)d_in[8];
    const float* Wg    = (const float*)d_in[9];
    const float* bg    = (const float*)d_in[10];
    const float* gamma = (const float*)d_in[11];
    const float* beta  = (const float*)d_in[12];
    float* out = (float*)d_out;

    // workspace (ushort, all fp16): xn|q|k|vt|g | wbuf[Wq,Wk,Wv,Wg,Wo]
    const size_t S = (size_t)BT_ * C_;
    u16* xn   = (u16*)d_ws;
    u16* qh   = xn + S;
    u16* kh   = qh + S;
    u16* vth  = kh + S;
    u16* g_bf = vth + S;
    u16* wbuf = g_bf + S;
    u16* y_h  = xn;          // alias: xn dead after qkvg

    wconv_all<<<dim3(WSZ / 1024, 5), 256, 0, stream>>>(Wq, Wk, Wv, Wg, Wo, wbuf);
    ln_kernel<<<dim3(64, 8), 256, 0, stream>>>(x, gamma, beta, xn);
    qkvg_mfma<<<dim3(64, 24), 256, 0, stream>>>(xn, wbuf, bq, bk, bv, bg,
                                                qh, kh, vth, g_bf);
    attn_mfma<<<dim3(16, 12, 8), 256, 0, stream>>>(qh, kh, vth, g_bf, y_h);
    out_mfma<<<dim3(6, 64), 256, 0, stream>>>(y_h, wbuf + (size_t)4 * WSZ, bo, out);
}

// Round 10
// 298.885 us; speedup vs baseline: 1.3211x; 1.0651x over previous
//
#include <hip/hip_runtime.h>
#include <math.h>

#define B_   8
#define C_   768
#define T_   1024
#define BT_  (B_*T_)       // 8192
#define WSZ  (C_*C_)       // 589824 per weight matrix

using f16x8 = __attribute__((ext_vector_type(8))) _Float16;
using f32x4 = __attribute__((ext_vector_type(4))) float;
typedef unsigned short u16;

// ---- fp16 helpers ----
__device__ inline u16 f16b(float x) {
    _Float16 h = (_Float16)x;
    return __builtin_bit_cast(u16, h);
}
__device__ inline float f16f(u16 b) {
    return (float)__builtin_bit_cast(_Float16, b);
}

// ---------------------------------------------------------------------------
// Kernel 0: all 5 weight mats fp32 -> fp16 in one launch.
// ---------------------------------------------------------------------------
__global__ __launch_bounds__(256) void wconv_all(
    const float* __restrict__ W0, const float* __restrict__ W1,
    const float* __restrict__ W2, const float* __restrict__ W3,
    const float* __restrict__ W4, u16* __restrict__ wbuf) {
    int mat = blockIdx.y;
    const float* W = (mat == 0) ? W0 : (mat == 1) ? W1 : (mat == 2) ? W2
                   : (mat == 3) ? W3 : W4;
    u16* o = wbuf + (size_t)mat * WSZ;
    int i = (blockIdx.x * 256 + threadIdx.x) * 4;
    float4 w = *(const float4*)(W + i);
    ushort4 h;
    h.x = f16b(w.x);
    h.y = f16b(w.y);
    h.z = f16b(w.z);
    h.w = f16b(w.w);
    *(ushort4*)(o + i) = h;
}

// ---------------------------------------------------------------------------
// Kernel 1: LayerNorm, coalesced 16-token tile (R9, kept -- saved ~11 us).
// ---------------------------------------------------------------------------
__global__ __launch_bounds__(256) void ln_kernel(const float* __restrict__ x,
                                                 const float* __restrict__ gamma,
                                                 const float* __restrict__ beta,
                                                 u16* __restrict__ xh) {
    int b = blockIdx.y;
    int t0 = blockIdx.x * 16;
    int tid = threadIdx.x;
    int tx = tid & 15;          // t offset
    int cg = tid >> 4;          // c group 0..15
    const float* xb = x + (size_t)b * C_ * T_ + t0 + tx;

    float v[48];
    float s = 0.f, sq = 0.f;
    #pragma unroll
    for (int i = 0; i < 48; ++i) {
        float val = xb[(size_t)(i * 16 + cg) * T_];
        v[i] = val; s += val; sq += val * val;
    }
    __shared__ float rs_[16][16], rq_[16][16];   // [cg][tx]
    rs_[cg][tx] = s;
    rq_[cg][tx] = sq;
    __syncthreads();
    __shared__ float mu_[16], rstd_[16];
    if (tid < 16) {
        float S = 0.f, Q = 0.f;
        #pragma unroll
        for (int k = 0; k < 16; ++k) { S += rs_[k][tid]; Q += rq_[k][tid]; }
        float mu = S * (1.0f / 768.0f);
        float var = Q * (1.0f / 768.0f) - mu * mu;
        mu_[tid] = mu;
        rstd_[tid] = 1.0f / sqrtf(var + 1e-5f);
    }
    __syncthreads();
    float mu = mu_[tx], rstd = rstd_[tx];
    __shared__ u16 Lt[16][776];                  // +8 u16 pad
    #pragma unroll
    for (int i = 0; i < 48; ++i) {
        int c = i * 16 + cg;
        Lt[tx][c] = f16b((v[i] - mu) * rstd * gamma[c] + beta[c]);
    }
    __syncthreads();
    size_t obase = ((size_t)b * 1024 + t0) * C_;
    #pragma unroll
    for (int st = 0; st < 12; ++st) {
        int idx = st * 256 + tid;
        int t = idx / 192, c4 = idx % 192;
        *(ushort4*)(xh + obase + (size_t)t * C_ + c4 * 4) = *(ushort4*)&Lt[t][c4 * 4];
    }
}

// ---------------------------------------------------------------------------
// Kernel 2: fused QKVG GEMM, fp16 MFMA. REVERTED to the R6/R8 proven best
// (both operands staged, single-barrier DB + 2-stage reg prefetch, (256,3),
// VGPR 84, 114.5 us). Ledger: 2-barrier TLP 130 | serial gld_lds 230 |
// this 114.5 | no-LDS 146 | hybrid A-direct 121.5. Latency/barrier-bound
// at this occupancy -- schedule micro-variants are exhausted.
// ---------------------------------------------------------------------------
__global__ __launch_bounds__(256, 3) void qkvg_mfma(
    const u16* __restrict__ xh, const u16* __restrict__ wmats,
    const float* __restrict__ bq, const float* __restrict__ bk,
    const float* __restrict__ bv, const float* __restrict__ bg,
    u16* __restrict__ qh, u16* __restrict__ kh,
    u16* __restrict__ vth, u16* __restrict__ g) {
    int bx = blockIdx.x;            // m tile 0..63
    int by = blockIdx.y;            // 0..23
    int mat = by / 6;
    int n0  = (by % 6) * 128;
    int m0  = bx * 128;
    const u16* Wh = wmats + (size_t)mat * WSZ;
    const float* bias = (mat == 0) ? bq : (mat == 1) ? bk : (mat == 2) ? bv : bg;

    __shared__ __attribute__((aligned(16))) u16 Ah[2 * 4096], Bh[2 * 4096];  // 32 KB

    int tid  = threadIdx.x;
    int lane = tid & 63, wid = tid >> 6;
    int wm = (wid & 1) * 64, wn = (wid >> 1) * 64;
    int fr = lane & 15, rq = (lane >> 4) * 4;

    f32x4 acc[4][4];
    #pragma unroll
    for (int i = 0; i < 4; ++i)
        #pragma unroll
        for (int j = 0; j < 4; ++j)
            acc[i][j] = (f32x4){0.f, 0.f, 0.f, 0.f};

    int j = tid >> 5, u = tid & 31;
    size_t offA = (size_t)(m0 + j * 16 + (u & 15)) * 768 + (u >> 4) * 8;
    size_t offB = (size_t)(n0 + j * 16 + (u & 15)) * 768 + (u >> 4) * 8;
    int lo0 = j * 512 + u * 8;      // u16 units
    int ba = (wm >> 4), bb2 = (wn >> 4);

    uint4 a0, a1, c0, c1;
    #define LOADT(T) do { int kk0 = (T) * 32; \
        a0 = *(const uint4*)(xh + offA + kk0); \
        a1 = *(const uint4*)(xh + offA + kk0 + 16); \
        c0 = *(const uint4*)(Wh + offB + kk0); \
        c1 = *(const uint4*)(Wh + offB + kk0 + 16); \
    } while (0)
    #define STORET(BUF) do { int lb = (BUF) * 4096 + lo0; \
        *(uint4*)(Ah + lb) = a0;  *(uint4*)(Ah + lb + 256) = a1; \
        *(uint4*)(Bh + lb) = c0;  *(uint4*)(Bh + lb + 256) = c1; \
    } while (0)

    LOADT(0);
    STORET(0);
    LOADT(1);
    __syncthreads();
    int cur = 0;
    for (int t = 0; t < 24; ++t) {
        int nxt = cur ^ 1;
        STORET(nxt);                       // stage tile t+1 (t=23: garbage, never read)
        LOADT((t + 2 < 24) ? t + 2 : 0);   // issue tile t+2 loads
        int cb = cur * 4096;
        f16x8 fah[4], fbh[4];
        #pragma unroll
        for (int i = 0; i < 4; ++i) {
            fah[i] = *(const f16x8*)(Ah + cb + (ba + i) * 512 + lane * 8);
            fbh[i] = *(const f16x8*)(Bh + cb + (bb2 + i) * 512 + lane * 8);
        }
        if (mat == 2) {   // v: swapped operands -> transposed (token-minor) store
            #pragma unroll
            for (int mi = 0; mi < 4; ++mi)
                #pragma unroll
                for (int ni = 0; ni < 4; ++ni)
                    acc[mi][ni] = __builtin_amdgcn_mfma_f32_16x16x32_f16(fbh[ni], fah[mi], acc[mi][ni], 0, 0, 0);
        } else {
            #pragma unroll
            for (int mi = 0; mi < 4; ++mi)
                #pragma unroll
                for (int ni = 0; ni < 4; ++ni)
                    acc[mi][ni] = __builtin_amdgcn_mfma_f32_16x16x32_f16(fah[mi], fbh[ni], acc[mi][ni], 0, 0, 0);
        }
        __syncthreads();
        cur = nxt;
    }
    #undef LOADT
    #undef STORET
    // epilogue: C/D layout col=lane&15, row=(lane>>4)*4+reg
    if (mat == 2) {
        int bb = m0 >> 10;
        #pragma unroll
        for (int mi = 0; mi < 4; ++mi) {
            int tok = m0 + wm + mi * 16 + fr;
            int tl  = tok & 1023;
            #pragma unroll
            for (int ni = 0; ni < 4; ++ni) {
                #pragma unroll
                for (int rg = 0; rg < 4; ++rg) {
                    int ch = n0 + wn + ni * 16 + rq + rg;
                    float val = acc[mi][ni][rg] + bias[ch];
                    size_t addr = ((size_t)((bb * 12 + (ch >> 6)) * 64 + (ch & 63))) * 1024 + tl;
                    vth[addr] = f16b(val);
                }
            }
        }
    } else {
        u16* oh = (mat == 0) ? qh : (mat == 1) ? kh : g;
        float scale = (mat == 0) ? 0.125f : 1.0f;
        #pragma unroll
        for (int ni = 0; ni < 4; ++ni) {
            int col = n0 + wn + ni * 16 + fr;
            float bb = bias[col];
            #pragma unroll
            for (int mi = 0; mi < 4; ++mi) {
                int row = m0 + wm + mi * 16 + rq;
                #pragma unroll
                for (int rg = 0; rg < 4; ++rg) {
                    float val = (acc[mi][ni][rg] + bb) * scale;
                    oh[(size_t)(row + rg) * 768 + col] = f16b(val);
                }
            }
        }
    }
}

// ---------------------------------------------------------------------------
// Kernel 3: MFMA flash attention, fp16, swapped QK^T. R10: QBLK=128 -- each
// wave runs TWO 16-row Q-strips against the same staged K/V tile. Staging
// and barriers per st unchanged, MFMA per st doubles, K/V re-staging halves
// globally (was 16 blocks re-staging 256KB K/V per (b,h); now 8).
// Ps rows are wave-private and reused sequentially per strip (in-wave LDS
// ordering handles the RAW). (256,2): ~105 live VGPR, cap 128; LDS 41KB
// caps residency at 3 anyway.
// ---------------------------------------------------------------------------
__global__ __launch_bounds__(256, 2) void attn_mfma(
    const u16* __restrict__ qhg, const u16* __restrict__ khg,
    const u16* __restrict__ vthg, const u16* __restrict__ gbf,
    u16* __restrict__ yh) {
    int qt = blockIdx.x;   // 0..7 (128 q-rows)
    int h  = blockIdx.y;   // 0..11
    int b  = blockIdx.z;   // 0..7
    __shared__ u16 Kh[2 * 4096], Vh[2 * 4096];
    __shared__ u16 Ps[64 * 72];
    int tid = threadIdx.x;
    int lane = tid & 63, w = tid >> 6;
    int fr = lane & 15, quad = lane >> 4, fq = quad * 8;

    size_t qbaseA = ((size_t)(b * 1024 + qt * 128)) * 768 + h * 64;
    size_t qbaseB = qbaseA + (size_t)64 * 768;
    size_t kbase = ((size_t)(b * 1024)) * 768 + h * 64;
    size_t vbase = ((size_t)((b * 12 + h) * 64)) * 1024;

    f16x8 aqA[2], aqB[2];
    #pragma unroll
    for (int kk = 0; kk < 2; ++kk) {
        size_t ro = (size_t)(w * 16 + fr) * 768 + kk * 32 + fq;
        aqA[kk] = *(const f16x8*)(qhg + qbaseA + ro);
        aqB[kk] = *(const f16x8*)(qhg + qbaseB + ro);
    }

    float m_A = -1e30f, l_A = 0.0f, m_B = -1e30f, l_B = 0.0f;
    f32x4 OA[4], OB[4];
    #pragma unroll
    for (int i = 0; i < 4; ++i) {
        OA[i] = (f32x4){0.f, 0.f, 0.f, 0.f};
        OB[i] = (f32x4){0.f, 0.f, 0.f, 0.f};
    }

    int j = tid >> 5, u = tid & 31;
    int kk_ = j >> 2, nd_ = j & 3;
    size_t offK = kbase + (size_t)(nd_ * 16 + (u & 15)) * 768 + kk_ * 32 + (u >> 4) * 8;
    size_t offV = vbase + (size_t)(nd_ * 16 + (u & 15)) * 1024 + kk_ * 32 + (u >> 4) * 8;
    int lo0 = j * 512 + u * 8;

    uint4 rk0, rk1, rv0, rv1;
    #define LOADKV(ST) do { \
        size_t ok = offK + (size_t)(ST) * 49152; \
        size_t ov = offV + (size_t)(ST) * 64; \
        rk0 = *(const uint4*)(khg + ok);  rk1 = *(const uint4*)(khg + ok + 16); \
        rv0 = *(const uint4*)(vthg + ov); rv1 = *(const uint4*)(vthg + ov + 16); \
    } while (0)
    #define STOREKV(BUF) do { \
        int lb = (BUF) * 4096 + lo0; \
        *(uint4*)(Kh + lb) = rk0;  *(uint4*)(Kh + lb + 256) = rk1; \
        *(uint4*)(Vh + lb) = rv0;  *(uint4*)(Vh + lb + 256) = rv1; \
    } while (0)

    // one Q-strip against the staged K/V tile in buf[cur]
    #define STRIP(AQ, MS, LS, OACC) do { \
        f32x4 sacc[4]; \
        _Pragma("unroll") \
        for (int nt = 0; nt < 4; ++nt) sacc[nt] = (f32x4){0.f, 0.f, 0.f, 0.f}; \
        _Pragma("unroll") \
        for (int nt = 0; nt < 4; ++nt) \
            _Pragma("unroll") \
            for (int kk = 0; kk < 2; ++kk) { \
                f16x8 kb = *(const f16x8*)(Kh + cur * 4096 + (kk * 4 + nt) * 512 + lane * 8); \
                sacc[nt] = __builtin_amdgcn_mfma_f32_16x16x32_f16(kb, AQ[kk], sacc[nt], 0, 0, 0); \
            } \
        float mx = -1e30f; \
        _Pragma("unroll") \
        for (int nt = 0; nt < 4; ++nt) \
            _Pragma("unroll") \
            for (int rg = 0; rg < 4; ++rg) mx = fmaxf(mx, sacc[nt][rg]); \
        mx = fmaxf(mx, __shfl_xor(mx, 16)); \
        mx = fmaxf(mx, __shfl_xor(mx, 32)); \
        float mn = fmaxf(MS, mx); \
        float al = __expf(MS - mn); \
        MS = mn; \
        float rs = 0.0f; \
        _Pragma("unroll") \
        for (int nt = 0; nt < 4; ++nt) \
            _Pragma("unroll") \
            for (int rg = 0; rg < 4; ++rg) { \
                float p = __expf(sacc[nt][rg] - mn); \
                sacc[nt][rg] = p; \
                rs += p; \
            } \
        rs += __shfl_xor(rs, 16); \
        rs += __shfl_xor(rs, 32); \
        LS = LS * al + rs; \
        int prow = (w * 16 + fr) * 72; \
        _Pragma("unroll") \
        for (int nt = 0; nt < 4; ++nt) { \
            ushort4 hp; \
            hp.x = f16b(sacc[nt][0]); \
            hp.y = f16b(sacc[nt][1]); \
            hp.z = f16b(sacc[nt][2]); \
            hp.w = f16b(sacc[nt][3]); \
            *(ushort4*)&Ps[prow + nt * 16 + quad * 4] = hp; \
        } \
        float alr[4]; \
        _Pragma("unroll") \
        for (int rg = 0; rg < 4; ++rg) alr[rg] = __shfl(al, quad * 4 + rg, 16); \
        _Pragma("unroll") \
        for (int dn = 0; dn < 4; ++dn) \
            _Pragma("unroll") \
            for (int rg = 0; rg < 4; ++rg) OACC[dn][rg] *= alr[rg]; \
        _Pragma("unroll") \
        for (int kk = 0; kk < 2; ++kk) { \
            f16x8 pa = *(const f16x8*)&Ps[(w * 16 + fr) * 72 + fq + kk * 32]; \
            _Pragma("unroll") \
            for (int dn = 0; dn < 4; ++dn) { \
                f16x8 vb = *(const f16x8*)(Vh + cur * 4096 + (kk * 4 + dn) * 512 + lane * 8); \
                OACC[dn] = __builtin_amdgcn_mfma_f32_16x16x32_f16(pa, vb, OACC[dn], 0, 0, 0); \
            } \
        } \
    } while (0)

    LOADKV(0);
    STOREKV(0);
    LOADKV(1);
    __syncthreads();
    int cur = 0;
    for (int st = 0; st < 16; ++st) {
        int nxt = cur ^ 1;
        STOREKV(nxt);                  // stage st+1 (garbage on last, never read)
        int s2 = (st + 2 < 16) ? (st + 2) : 0;
        LOADKV(s2);
        STRIP(aqA, m_A, l_A, OA);
        STRIP(aqB, m_B, l_B, OB);
        __syncthreads();
        cur = nxt;
    }
    #undef LOADKV
    #undef STOREKV
    #undef STRIP
    // epilogue: normalize, sigmoid gate, fp16 y store (both strips)
    float invA[4], invB[4];
    #pragma unroll
    for (int rg = 0; rg < 4; ++rg) {
        invA[rg] = 1.0f / __shfl(l_A, quad * 4 + rg, 16);
        invB[rg] = 1.0f / __shfl(l_B, quad * 4 + rg, 16);
    }
    int tokA0 = b * 1024 + qt * 128 + w * 16;
    #pragma unroll
    for (int dn = 0; dn < 4; ++dn) {
        int ch = h * 64 + dn * 16 + fr;
        #pragma unroll
        for (int rg = 0; rg < 4; ++rg) {
            int tok = tokA0 + quad * 4 + rg;
            float gv = f16f(gbf[(size_t)tok * 768 + ch]);
            float sg = 1.0f / (1.0f + __expf(-gv));
            yh[(size_t)tok * 768 + ch] = f16b(OA[dn][rg] * invA[rg] * sg);
            int tok2 = tok + 64;
            float gv2 = f16f(gbf[(size_t)tok2 * 768 + ch]);
            float sg2 = 1.0f / (1.0f + __expf(-gv2));
            yh[(size_t)tok2 * 768 + ch] = f16b(OB[dn][rg] * invB[rg] * sg2);
        }
    }
}

// ---------------------------------------------------------------------------
// Kernel 4: out = y @ Wo^T + bo -> (B, C, T), single fp16 MFMA.
// R6/R8 proven both-staged DB structure.
// ---------------------------------------------------------------------------
__global__ __launch_bounds__(256, 3) void out_mfma(
    const u16* __restrict__ yh, const u16* __restrict__ woh,
    const float* __restrict__ bo, float* __restrict__ out) {
    int bx = blockIdx.x;   // c tile 0..5
    int by = blockIdx.y;   // t tile 0..63
    int m0 = bx * 128;     // c
    int n0 = by * 128;     // t

    __shared__ __attribute__((aligned(16))) u16 Ah[2 * 4096], Bh[2 * 4096];  // 32 KB

    int tid  = threadIdx.x;
    int lane = tid & 63, wid = tid >> 6;
    int wm = (wid & 1) * 64, wn = (wid >> 1) * 64;
    int fr = lane & 15, rq = (lane >> 4) * 4;

    f32x4 acc[4][4];
    #pragma unroll
    for (int i = 0; i < 4; ++i)
        #pragma unroll
        for (int j = 0; j < 4; ++j)
            acc[i][j] = (f32x4){0.f, 0.f, 0.f, 0.f};

    int j = tid >> 5, u = tid & 31;
    size_t offA = (size_t)(m0 + j * 16 + (u & 15)) * 768 + (u >> 4) * 8;
    size_t offB = (size_t)(n0 + j * 16 + (u & 15)) * 768 + (u >> 4) * 8;
    int lo0 = j * 512 + u * 8;
    int ba = (wm >> 4), bb2 = (wn >> 4);

    uint4 a0, a1, c0, c1;
    #define LOADT(T) do { int kk0 = (T) * 32; \
        a0 = *(const uint4*)(woh + offA + kk0); \
        a1 = *(const uint4*)(woh + offA + kk0 + 16); \
        c0 = *(const uint4*)(yh + offB + kk0); \
        c1 = *(const uint4*)(yh + offB + kk0 + 16); \
    } while (0)
    #define STORET(BUF) do { int lb = (BUF) * 4096 + lo0; \
        *(uint4*)(Ah + lb) = a0;  *(uint4*)(Ah + lb + 256) = a1; \
        *(uint4*)(Bh + lb) = c0;  *(uint4*)(Bh + lb + 256) = c1; \
    } while (0)

    LOADT(0);
    STORET(0);
    LOADT(1);
    __syncthreads();
    int cur = 0;
    for (int t = 0; t < 24; ++t) {
        int nxt = cur ^ 1;
        STORET(nxt);
        LOADT((t + 2 < 24) ? t + 2 : 0);
        int cb = cur * 4096;
        f16x8 fah[4], fbh[4];
        #pragma unroll
        for (int i = 0; i < 4; ++i) {
            fah[i] = *(const f16x8*)(Ah + cb + (ba + i) * 512 + lane * 8);
            fbh[i] = *(const f16x8*)(Bh + cb + (bb2 + i) * 512 + lane * 8);
        }
        #pragma unroll
        for (int mi = 0; mi < 4; ++mi)
            #pragma unroll
            for (int ni = 0; ni < 4; ++ni)
                acc[mi][ni] = __builtin_amdgcn_mfma_f32_16x16x32_f16(fah[mi], fbh[ni], acc[mi][ni], 0, 0, 0);
        __syncthreads();
        cur = nxt;
    }
    #undef LOADT
    #undef STORET
    int bb = n0 >> 10;
    #pragma unroll
    for (int ni = 0; ni < 4; ++ni) {
        int colg = n0 + wn + ni * 16 + fr;
        int tl = colg & 1023;
        #pragma unroll
        for (int mi = 0; mi < 4; ++mi) {
            int row = m0 + wm + mi * 16 + rq;
            #pragma unroll
            for (int rg = 0; rg < 4; ++rg) {
                float val = acc[mi][ni][rg] + bo[row + rg];
                out[((size_t)bb * 768 + row + rg) * 1024 + tl] = val;
            }
        }
    }
}

extern "C" void kernel_launch(void* const* d_in, const int* in_sizes, int n_in,
                              void* d_out, int out_size, void* d_ws, size_t ws_size,
                              hipStream_t stream) {
    const float* x     = (const float*)d_in[0];
    const float* Wq    = (const float*)d_in[1];
    const float* bq    = (const float*)d_in[2];
    const float* Wk    = (const float*)d_in[3];
    const float* bk    = (const float*)d_in[4];
    const float* Wv    = (const float*)d_in[5];
    const float* bv    = (const float*)d_in[6];
    const float* Wo    = (const float*)d_in[7];
    const float* bo    = (const float*)d_in[8];
    const float* Wg    = (const float*)d_in[9];
    const float* bg    = (const float*)d_in[10];
    const float* gamma = (const float*)d_in[11];
    const float* beta  = (const float*)d_in[12];
    float* out = (float*)d_out;

    // workspace (ushort, all fp16): xn|q|k|vt|g | wbuf[Wq,Wk,Wv,Wg,Wo]
    const size_t S = (size_t)BT_ * C_;
    u16* xn   = (u16*)d_ws;
    u16* qh   = xn + S;
    u16* kh   = qh + S;
    u16* vth  = kh + S;
    u16* g_bf = vth + S;
    u16* wbuf = g_bf + S;
    u16* y_h  = xn;          // alias: xn dead after qkvg

    wconv_all<<<dim3(WSZ / 1024, 5), 256, 0, stream>>>(Wq, Wk, Wv, Wg, Wo, wbuf);
    ln_kernel<<<dim3(64, 8), 256, 0, stream>>>(x, gamma, beta, xn);
    qkvg_mfma<<<dim3(64, 24), 256, 0, stream>>>(xn, wbuf, bq, bk, bv, bg,
                                                qh, kh, vth, g_bf);
    attn_mfma<<<dim3(8, 12, 8), 256, 0, stream>>>(qh, kh, vth, g_bf, y_h);
    out_mfma<<<dim3(6, 64), 256, 0, stream>>>(y_h, wbuf + (size_t)4 * WSZ, bo, out);
}